// Round 2
// baseline (1202.523 us; speedup 1.0000x reference)
//
#include <hip/hip_runtime.h>
#include <hip/hip_bf16.h>

#define NNODES 320000
#define NEDGES 960000

typedef __attribute__((ext_vector_type(8))) short short8;
typedef __attribute__((ext_vector_type(4))) float f32x4;

__device__ __forceinline__ float b2f(unsigned short u) {
    return __uint_as_float(((unsigned)u) << 16);
}
__device__ __forceinline__ unsigned short f2b(float f) {
    __hip_bfloat16 h = __float2bfloat16(f);
    union { __hip_bfloat16 h; unsigned short u; } cv;
    cv.h = h;
    return cv.u;
}

// ---------------- CSR build ----------------

__global__ void k_zero(int* p, int n) {
    int i = blockIdx.x * blockDim.x + threadIdx.x;
    int s = gridDim.x * blockDim.x;
    for (; i < n; i += s) p[i] = 0;
}

__global__ void k_count(const int* __restrict__ edges, int* __restrict__ deg) {
    int i = blockIdx.x * blockDim.x + threadIdx.x;
    int s = gridDim.x * blockDim.x;
    for (; i < NEDGES; i += s) {
        int a = edges[2 * i], b = edges[2 * i + 1];
        atomicAdd(&deg[a], 1);
        atomicAdd(&deg[b], 1);
    }
}

#define SCAN_BLOCK 256
#define SCAN_ITEMS 8
#define SCAN_CHUNK 2048
#define SCAN_NB 157  // ceil(320000/2048)

__global__ void k_scan1(const int* __restrict__ deg, int* __restrict__ bsum) {
    __shared__ int sd[SCAN_BLOCK];
    int b = blockIdx.x, t = threadIdx.x;
    int base = b * SCAN_CHUNK + t * SCAN_ITEMS;
    int s = 0;
    for (int i = 0; i < SCAN_ITEMS; i++) {
        int g = base + i;
        if (g < NNODES) s += deg[g];
    }
    sd[t] = s;
    __syncthreads();
    for (int off = 128; off > 0; off >>= 1) {
        if (t < off) sd[t] += sd[t + off];
        __syncthreads();
    }
    if (t == 0) bsum[b] = sd[0];
}

__global__ void k_scan2(int* bsum, int* rowptr) {
    if (blockIdx.x == 0 && threadIdx.x == 0) {
        int run = 0;
        for (int b = 0; b < SCAN_NB; b++) {
            int v = bsum[b];
            bsum[b] = run;
            run += v;
        }
        rowptr[NNODES] = run;  // == 2*NEDGES
    }
}

__global__ void k_scan3(int* __restrict__ deg_cursor, int* __restrict__ rowptr,
                        const int* __restrict__ bsum) {
    __shared__ int sd[SCAN_BLOCK];
    int b = blockIdx.x, t = threadIdx.x;
    int base = b * SCAN_CHUNK + t * SCAN_ITEMS;
    int v[SCAN_ITEMS];
    int s = 0;
    for (int i = 0; i < SCAN_ITEMS; i++) {
        int g = base + i;
        v[i] = (g < NNODES) ? deg_cursor[g] : 0;
        s += v[i];
    }
    sd[t] = s;
    __syncthreads();
    // Hillis-Steele inclusive scan over thread sums
    for (int off = 1; off < SCAN_BLOCK; off <<= 1) {
        int x = (t >= off) ? sd[t - off] : 0;
        __syncthreads();
        sd[t] += x;
        __syncthreads();
    }
    int prefix = bsum[b] + (sd[t] - s);  // exclusive over threads
    for (int i = 0; i < SCAN_ITEMS; i++) {
        int g = base + i;
        if (g < NNODES) {
            rowptr[g] = prefix;
            deg_cursor[g] = prefix;  // cursor init
            prefix += v[i];
        }
    }
}

__global__ void k_fill(const int* __restrict__ edges, int* __restrict__ cursor,
                       int* __restrict__ adj) {
    int i = blockIdx.x * blockDim.x + threadIdx.x;
    int s = gridDim.x * blockDim.x;
    for (; i < NEDGES; i += s) {
        int a = edges[2 * i], b = edges[2 * i + 1];
        adj[atomicAdd(&cursor[a], 1)] = b;
        adj[atomicAdd(&cursor[b], 1)] = a;
    }
}

// ---------------- dual GEMM: h01[N][256] = x[N][128] @ [W0|W1] + [b0|b1] (bf16 out) ----------------
// blockIdx.x & 1 selects column half (W0 or W1). 64-row tiles, grid-stride.
// 4 waves: 2 (M) x 2 (N); wave tile 32 rows x 64 cols; mfma 16x16x32 bf16.

#define LDK 136  // padded row stride (bf16 elems): 272B = 17*16 -> aligned b128, conflict-light

__global__ __launch_bounds__(256) void k_gemm(
    const void* __restrict__ xin, int xIsF32,
    const float* __restrict__ W0p, const float* __restrict__ W1p,
    const float* __restrict__ b0p, const float* __restrict__ b1p,
    unsigned short* __restrict__ h01) {
    __shared__ __align__(16) unsigned short Wt[128 * LDK];  // [col][k] transposed, bf16
    __shared__ __align__(16) unsigned short At[64 * LDK];   // [row][k] bf16
    __shared__ float biasS[128];

    int tid = threadIdx.x;
    int half = blockIdx.x & 1;
    const float* W = half ? W1p : W0p;
    const float* bb = half ? b1p : b0p;

    // stage W transposed to [c][k], convert f32->bf16 (once per block)
    for (int it = 0; it < 64; ++it) {
        int idx = it * 256 + tid;
        int c = idx & 127;
        int k = idx >> 7;
        Wt[c * LDK + k] = f2b(W[k * 128 + c]);
    }
    if (tid < 128) biasS[tid] = bb[tid];

    int wave = tid >> 6, lane = tid & 63;
    int wm = wave >> 1, wn = wave & 1;
    int nchunks = gridDim.x >> 1;

    for (int rt = blockIdx.x >> 1; rt < NNODES / 64; rt += nchunks) {
        __syncthreads();  // W staged (1st iter) / previous A reads done
        int rowBase = rt * 64;
        if (xIsF32) {
            const float* xf = (const float*)xin;
            for (int it = 0; it < 8; ++it) {
                int e = (it * 256 + tid) * 4;
                int r = e >> 7;
                int k = e & 127;
                float4 v = *(const float4*)&xf[(size_t)(rowBase + r) * 128 + k];
                unsigned short* dst = &At[r * LDK + k];
                dst[0] = f2b(v.x);
                dst[1] = f2b(v.y);
                dst[2] = f2b(v.z);
                dst[3] = f2b(v.w);
            }
        } else {
            const unsigned short* xb = (const unsigned short*)xin;
            for (int it = 0; it < 4; ++it) {
                int e = (it * 256 + tid) * 8;
                int r = e >> 7;
                int k = e & 127;
                *(uint4*)&At[r * LDK + k] =
                    *(const uint4*)&xb[(size_t)(rowBase + r) * 128 + k];
            }
        }
        __syncthreads();

        f32x4 acc[2][4];
        for (int i = 0; i < 2; i++)
            for (int j = 0; j < 4; j++) acc[i][j] = (f32x4){0.f, 0.f, 0.f, 0.f};

        for (int ks = 0; ks < 4; ++ks) {
            int kk = ks * 32 + ((lane >> 4) << 3);
            short8 aF[2], bF[4];
            for (int mf = 0; mf < 2; ++mf) {
                int r = wm * 32 + mf * 16 + (lane & 15);
                aF[mf] = *(const short8*)&At[r * LDK + kk];
            }
            for (int nf = 0; nf < 4; ++nf) {
                int c = wn * 64 + nf * 16 + (lane & 15);
                bF[nf] = *(const short8*)&Wt[c * LDK + kk];
            }
            for (int mf = 0; mf < 2; mf++)
                for (int nf = 0; nf < 4; nf++)
                    acc[mf][nf] = __builtin_amdgcn_mfma_f32_16x16x32_bf16(
                        aF[mf], bF[nf], acc[mf][nf], 0, 0, 0);
        }

        // epilogue: D row = (lane>>4)*4+q, col = lane&15 (verified layout)
        for (int mf = 0; mf < 2; mf++)
            for (int nf = 0; nf < 4; nf++) {
                int r0 = rowBase + wm * 32 + mf * 16 + ((lane >> 4) << 2);
                int cl = wn * 64 + nf * 16 + (lane & 15);
                int c = half * 128 + cl;
                float bv = biasS[cl];
                f32x4 d = acc[mf][nf];
                for (int q = 0; q < 4; q++)
                    h01[(size_t)(r0 + q) * 256 + c] = f2b(d[q] + bv);
            }
    }
}

// ---------------- aggregation: out[i] = relu(h0[i] + sum_nbr h1[j]) (+features) ----------------
// one wave per node; lane handles cols {2*lane, 2*lane+1}

template <int MODE>  // 0: relu only; 2: relu then + features (residual)
__global__ void k_agg(const unsigned short* __restrict__ h01,
                      const int* __restrict__ rowptr, const int* __restrict__ adj,
                      const float* __restrict__ features,
                      unsigned short* __restrict__ act) {
    int wid = (blockIdx.x * blockDim.x + threadIdx.x) >> 6;
    int lane = threadIdx.x & 63;
    int nw = (gridDim.x * blockDim.x) >> 6;
    for (int node = wid; node < NNODES; node += nw) {
        unsigned u = *(const unsigned*)&h01[(size_t)node * 256 + lane * 2];
        float a0 = b2f(u & 0xffff), a1 = b2f(u >> 16);
        int s = rowptr[node], e = rowptr[node + 1];
        int p = s;
        for (; p + 2 <= e; p += 2) {
            int j0 = adj[p], j1 = adj[p + 1];
            unsigned v0 = *(const unsigned*)&h01[(size_t)j0 * 256 + 128 + lane * 2];
            unsigned v1 = *(const unsigned*)&h01[(size_t)j1 * 256 + 128 + lane * 2];
            a0 += b2f(v0 & 0xffff) + b2f(v1 & 0xffff);
            a1 += b2f(v0 >> 16) + b2f(v1 >> 16);
        }
        if (p < e) {
            int j = adj[p];
            unsigned v = *(const unsigned*)&h01[(size_t)j * 256 + 128 + lane * 2];
            a0 += b2f(v & 0xffff);
            a1 += b2f(v >> 16);
        }
        a0 = fmaxf(a0, 0.f);
        a1 = fmaxf(a1, 0.f);
        if (MODE == 2) {
            float2 f = *(const float2*)&features[(size_t)node * 128 + lane * 2];
            a0 += f.x;
            a1 += f.y;
        }
        unsigned out = (unsigned)f2b(a0) | ((unsigned)f2b(a1) << 16);
        *(unsigned*)&act[(size_t)node * 128 + lane * 2] = out;
    }
}

// ---------------- final layer: h3[N][8] = {h0[0..2], _, h1[0..2], _} f32 ----------------

#define LDK3 136

__global__ __launch_bounds__(256) void k_gemm3(
    const unsigned short* __restrict__ act, const float* __restrict__ W0p,
    const float* __restrict__ W1p, const float* __restrict__ b0p,
    const float* __restrict__ b1p, float* __restrict__ h3) {
    __shared__ __align__(16) unsigned short xs[128 * LDK3];
    __shared__ float Ws[128 * 8];
    __shared__ float bs[8];
    int tid = threadIdx.x;
    int nodeBase = blockIdx.x * 128;

    for (int idx = tid; idx < 384; idx += 256) {
        int k = idx / 3, c = idx - k * 3;
        Ws[k * 8 + c] = W0p[idx];
        Ws[k * 8 + 4 + c] = W1p[idx];
    }
    if (tid < 3) {
        bs[tid] = b0p[tid];
        bs[4 + tid] = b1p[tid];
    }
    for (int it = 0; it < 8; ++it) {
        int e = (it * 256 + tid) * 8;
        int r = e >> 7;
        int k = e & 127;
        *(uint4*)&xs[r * LDK3 + k] = *(const uint4*)&act[(size_t)(nodeBase + r) * 128 + k];
    }
    __syncthreads();

    int n = tid >> 1, half = tid & 1;
    float a0 = 0.f, a1 = 0.f, a2 = 0.f;
    for (int k0 = 0; k0 < 128; k0 += 8) {
        uint4 v = *(const uint4*)&xs[n * LDK3 + k0];
        unsigned vv[4] = {v.x, v.y, v.z, v.w};
#pragma unroll
        for (int q = 0; q < 4; q++) {
            int k = k0 + 2 * q;
            float x0 = b2f(vv[q] & 0xffff), x1 = b2f(vv[q] >> 16);
            const float* w = &Ws[k * 8 + half * 4];
            a0 += x0 * w[0] + x1 * w[8];
            a1 += x0 * w[1] + x1 * w[9];
            a2 += x0 * w[2] + x1 * w[10];
        }
    }
    float* dst = &h3[(size_t)(nodeBase + n) * 8 + half * 4];
    dst[0] = a0 + bs[half * 4 + 0];
    dst[1] = a1 + bs[half * 4 + 1];
    dst[2] = a2 + bs[half * 4 + 2];
}

__global__ void k_agg3(const float* __restrict__ h3, const int* __restrict__ rowptr,
                       const int* __restrict__ adj, float* __restrict__ out) {
    int i = blockIdx.x * blockDim.x + threadIdx.x;
    int stride = gridDim.x * blockDim.x;
    for (int node = i; node < NNODES; node += stride) {
        float a0 = h3[(size_t)node * 8 + 0];
        float a1 = h3[(size_t)node * 8 + 1];
        float a2 = h3[(size_t)node * 8 + 2];
        int s = rowptr[node], e = rowptr[node + 1];
        for (int p = s; p < e; ++p) {
            int j = adj[p];
            float4 v = *(const float4*)&h3[(size_t)j * 8 + 4];
            a0 += v.x;
            a1 += v.y;
            a2 += v.z;
        }
        out[(size_t)node * 3 + 0] = a0;
        out[(size_t)node * 3 + 1] = a1;
        out[(size_t)node * 3 + 2] = a2;
    }
}

// ---------------- launch ----------------

extern "C" void kernel_launch(void* const* d_in, const int* in_sizes, int n_in,
                              void* d_out, int out_size, void* d_ws, size_t ws_size,
                              hipStream_t stream) {
    const float* features = (const float*)d_in[0];
    const int* edges = (const int*)d_in[1];
    const float *W0[4], *B0[4], *W1[4], *B1[4];
    for (int i = 0; i < 4; i++) {
        W0[i] = (const float*)d_in[2 + 4 * i];
        B0[i] = (const float*)d_in[3 + 4 * i];
        W1[i] = (const float*)d_in[4 + 4 * i];
        B1[i] = (const float*)d_in[5 + 4 * i];
    }

    char* p = (char*)d_ws;
    auto alloc = [&](size_t bytes) {
        void* r = (void*)p;
        p += (bytes + 255) & ~(size_t)255;
        return r;
    };
    int* rowptr = (int*)alloc((NNODES + 1) * sizeof(int));
    int* cursor = (int*)alloc((NNODES + 1) * sizeof(int));  // doubles as deg
    int* adj = (int*)alloc((size_t)2 * NEDGES * sizeof(int));
    int* bsum = (int*)alloc(1024);
    unsigned short* h01 = (unsigned short*)alloc((size_t)NNODES * 256 * 2);
    unsigned short* actb = (unsigned short*)alloc((size_t)NNODES * 128 * 2);
    float* h3 = (float*)h01;  // alias: h01 dead once layer-2 agg is done

    // CSR build
    k_zero<<<1024, 256, 0, stream>>>(cursor, NNODES + 1);
    k_count<<<2048, 256, 0, stream>>>(edges, cursor);
    k_scan1<<<SCAN_NB, SCAN_BLOCK, 0, stream>>>(cursor, bsum);
    k_scan2<<<1, 64, 0, stream>>>(bsum, rowptr);
    k_scan3<<<SCAN_NB, SCAN_BLOCK, 0, stream>>>(cursor, rowptr, bsum);
    k_fill<<<2048, 256, 0, stream>>>(edges, cursor, adj);

    // layer 0
    k_gemm<<<2048, 256, 0, stream>>>(features, 1, W0[0], W1[0], B0[0], B1[0], h01);
    k_agg<0><<<16384, 256, 0, stream>>>(h01, rowptr, adj, nullptr, actb);
    // layer 1
    k_gemm<<<2048, 256, 0, stream>>>(actb, 0, W0[1], W1[1], B0[1], B1[1], h01);
    k_agg<0><<<16384, 256, 0, stream>>>(h01, rowptr, adj, nullptr, actb);
    // layer 2 (+residual)
    k_gemm<<<2048, 256, 0, stream>>>(actb, 0, W0[2], W1[2], B0[2], B1[2], h01);
    k_agg<2><<<16384, 256, 0, stream>>>(h01, rowptr, adj, features, actb);
    // layer 3 (128 -> 3, no relu)
    k_gemm3<<<NNODES / 128, 256, 0, stream>>>(actb, W0[3], W1[3], B0[3], B1[3], h3);
    k_agg3<<<2048, 256, 0, stream>>>(h3, rowptr, adj, (float*)d_out);
}